// Round 2
// baseline (1198.134 us; speedup 1.0000x reference)
//
#include <hip/hip_runtime.h>
#include <hip/hip_bf16.h>
#include <stdint.h>

// Problem constants (reference: N=4096, D=1024, V=50257)
#define NROWS 4096
#define DDIM  1024
#define VDIM  50257
#define VPAD  50304   // 393 * 128

typedef __bf16 bf16;
typedef __bf16 bf16x4 __attribute__((ext_vector_type(4)));
typedef __bf16 bf16x8 __attribute__((ext_vector_type(8)));
typedef float  f32x4  __attribute__((ext_vector_type(4)));

// ---- async global -> LDS, 16B per lane (dest = wave-uniform base + lane*16) ----
__device__ __forceinline__ void async_load16(const void* gsrc, const void* lds_dst) {
  __builtin_amdgcn_global_load_lds(
      (__attribute__((address_space(1))) unsigned int*)(uintptr_t)gsrc,
      (__attribute__((address_space(3))) unsigned int*)(uint32_t)(uintptr_t)lds_dst,
      16, 0, 0);
}

// ---- fp32 -> bf16 conversion (4 elems/thread); pads beyond n_src with zeros ----
__global__ __launch_bounds__(256)
void cvt_kernel(const float* __restrict__ src, bf16* __restrict__ dst, size_t n_src) {
  size_t i = ((size_t)blockIdx.x * 256 + threadIdx.x) * 4;
  float4 f = make_float4(0.f, 0.f, 0.f, 0.f);
  if (i < n_src) f = *(const float4*)(src + i);
  bf16x4 o = { (__bf16)f.x, (__bf16)f.y, (__bf16)f.z, (__bf16)f.w };
  *(bf16x4*)(dst + i) = o;
}

// ---- exact fp32 target logit: lt[n] = dot(x[n], w[target[n]]) ----
__global__ __launch_bounds__(256)
void tlogit_kernel(const float* __restrict__ x, const float* __restrict__ w,
                   const int* __restrict__ tgt, float* __restrict__ lt) {
  int n = blockIdx.x;
  int t = tgt[n];
  const float4* xr = (const float4*)(x + (size_t)n * DDIM);
  const float4* wr = (const float4*)(w + (size_t)t * DDIM);
  float4 a = xr[threadIdx.x];
  float4 b = wr[threadIdx.x];
  float s = a.x * b.x + a.y * b.y + a.z * b.z + a.w * b.w;
  #pragma unroll
  for (int m = 32; m; m >>= 1) s += __shfl_down(s, m);
  __shared__ float red[4];
  if ((threadIdx.x & 63) == 0) red[threadIdx.x >> 6] = s;
  __syncthreads();
  if (threadIdx.x == 0) lt[n] = red[0] + red[1] + red[2] + red[3];
}

// ---- fused GEMM (bf16 MFMA) + exp + per-row partial sum -> atomicAdd S[n] ----
// Tile: BM=128 (x rows), BN=128 (vocab rows), BK=32. 256 threads = 4 waves (2x2).
// DOUBLE-BUFFERED single-barrier K-loop: issue chunk k+1's global_load_lds right
// after the barrier, compute chunk k from the other buffer. At the next barrier
// the prefetched loads have had one full compute phase in flight, so the
// vmcnt(0) drain overlaps with MFMA instead of exposing full LLC latency.
__global__ __launch_bounds__(256, 4)
void gemm_lse_kernel(const bf16* __restrict__ xb,   // [NROWS][DDIM]
                     const bf16* __restrict__ wb,   // [VPAD][DDIM] (pad rows zero)
                     float* __restrict__ S) {       // [NROWS] running sum of exp
  __shared__ __align__(16) unsigned char smem[32768];  // 2 x (A 8K + B 8K)

  const int tid  = threadIdx.x;
  const int wid  = tid >> 6;
  const int lane = tid & 63;
  const int col  = lane & 15;
  const int quad = lane >> 4;

  const int m0 = blockIdx.x * 128;   // row tiles fastest -> weight slab shared in L2/LLC
  const int v0 = blockIdx.y * 128;

  const int wave_m = wid >> 1;  // 0..1
  const int wave_n = wid & 1;   // 0..1

  // Staging: 8 slots-of-64 per operand tile; wave wid issues insts j=wid, j=wid+4.
  // inst j covers slot j*64+lane: k-chunk c=j>>1, row r=(j&1)*64+lane.
  const int j0 = wid, j1 = wid + 4;
  const int rA0 = (j0 & 1) * 64 + lane, c0 = j0 >> 1;
  const int rA1 = (j1 & 1) * 64 + lane, c1 = j1 >> 1;

  const bf16* gA0 = xb + (size_t)(m0 + rA0) * DDIM + c0 * 8;
  const bf16* gA1 = xb + (size_t)(m0 + rA1) * DDIM + c1 * 8;
  const bf16* gB0 = wb + (size_t)(v0 + rA0) * DDIM + c0 * 8;
  const bf16* gB1 = wb + (size_t)(v0 + rA1) * DDIM + c1 * 8;

  const uint32_t ldsA0 = (uint32_t)j0 * 1024;
  const uint32_t ldsA1 = (uint32_t)j1 * 1024;
  const uint32_t ldsB0 = 8192u + (uint32_t)j0 * 1024;
  const uint32_t ldsB1 = 8192u + (uint32_t)j1 * 1024;

  // Fragment read offsets: A[m=lane&15][k=quad*8+j], B[n=lane&15][k=quad*8+j]
  uint32_t aoff[4], boff[4];
  #pragma unroll
  for (int i = 0; i < 4; ++i) {
    aoff[i] = (uint32_t)((quad * 128) + wave_m * 64 + i * 16 + col) * 16u;
    boff[i] = 8192u + (uint32_t)((quad * 128) + wave_n * 64 + i * 16 + col) * 16u;
  }

  f32x4 acc[4][4] = {};

  // Prologue: prefetch chunk 0 into buffer 0.
  async_load16(gA0, smem + ldsA0);
  async_load16(gA1, smem + ldsA1);
  async_load16(gB0, smem + ldsB0);
  async_load16(gB1, smem + ldsB1);

  uint32_t p = 0;
  for (int k0 = 0; k0 < DDIM; k0 += 32) {
    __syncthreads();  // drains the buf-p loads (in flight one full compute phase)

    if (k0 + 32 < DDIM) {
      const uint32_t b = (p ^ 1) * 16384u;
      async_load16(gA0 + k0 + 32, smem + ldsA0 + b);
      async_load16(gA1 + k0 + 32, smem + ldsA1 + b);
      async_load16(gB0 + k0 + 32, smem + ldsB0 + b);
      async_load16(gB1 + k0 + 32, smem + ldsB1 + b);
    }

    const uint32_t base = p * 16384u;
    bf16x8 af[4], bfr[4];
    #pragma unroll
    for (int i = 0; i < 4; ++i) af[i]  = *(const bf16x8*)(smem + base + aoff[i]);
    #pragma unroll
    for (int i = 0; i < 4; ++i) bfr[i] = *(const bf16x8*)(smem + base + boff[i]);

    #pragma unroll
    for (int mi = 0; mi < 4; ++mi)
      #pragma unroll
      for (int ni = 0; ni < 4; ++ni)
        acc[mi][ni] = __builtin_amdgcn_mfma_f32_16x16x32_bf16(
            af[mi], bfr[ni], acc[mi][ni], 0, 0, 0);

    p ^= 1;
  }

  // Epilogue: exp + row-sum. D layout: row m = quad*4+reg, col n = lane&15.
  const int mbase = m0 + wave_m * 64;
  const int vbase = v0 + wave_n * 64;
  #pragma unroll
  for (int mi = 0; mi < 4; ++mi) {
    #pragma unroll
    for (int r = 0; r < 4; ++r) {
      float pacc = 0.f;
      #pragma unroll
      for (int ni = 0; ni < 4; ++ni) {
        int v = vbase + ni * 16 + col;
        float e = __expf(acc[mi][ni][r]);
        pacc += (v < VDIM) ? e : 0.f;   // mask vocab pad
      }
      pacc += __shfl_xor(pacc, 8);
      pacc += __shfl_xor(pacc, 4);
      pacc += __shfl_xor(pacc, 2);
      pacc += __shfl_xor(pacc, 1);
      if (col == 0)
        atomicAdd(&S[mbase + mi * 16 + quad * 4 + r], pacc);
    }
  }
}

// ---- final: loss = mean(log(S[n]) - lt[n]) ----
__global__ __launch_bounds__(1024)
void loss_kernel(const float* __restrict__ S, const float* __restrict__ lt,
                 float* __restrict__ out) {
  float s = 0.f;
  for (int n = threadIdx.x; n < NROWS; n += 1024)
    s += logf(S[n]) - lt[n];
  #pragma unroll
  for (int m = 32; m; m >>= 1) s += __shfl_down(s, m);
  __shared__ float red[16];
  if ((threadIdx.x & 63) == 0) red[threadIdx.x >> 6] = s;
  __syncthreads();
  if (threadIdx.x == 0) {
    float t = 0.f;
    #pragma unroll
    for (int i = 0; i < 16; ++i) t += red[i];
    out[0] = t / (float)NROWS;
  }
}

extern "C" void kernel_launch(void* const* d_in, const int* in_sizes, int n_in,
                              void* d_out, int out_size, void* d_ws, size_t ws_size,
                              hipStream_t stream) {
  const float* x = (const float*)d_in[0];   // [4096,1024] fp32
  const float* w = (const float*)d_in[1];   // [50257,1024] fp32
  const int*   t = (const int*)d_in[2];     // [4096] int
  float* out = (float*)d_out;

  char* ws = (char*)d_ws;
  const size_t wb_bytes = (size_t)VPAD * DDIM * sizeof(bf16);   // 103.0 MB
  const size_t xb_bytes = (size_t)NROWS * DDIM * sizeof(bf16);  //   8.4 MB
  bf16*  wb = (bf16*)ws;
  bf16*  xb = (bf16*)(ws + wb_bytes);
  float* S  = (float*)(ws + wb_bytes + xb_bytes);
  float* lt = S + NROWS;

  if (ws_size < wb_bytes + xb_bytes + 2 * NROWS * sizeof(float)) return; // fail loud

  hipMemsetAsync(S, 0, NROWS * sizeof(float), stream);
  cvt_kernel<<<(VPAD * (DDIM / 4)) / 256, 256, 0, stream>>>(w, wb, (size_t)VDIM * DDIM);
  cvt_kernel<<<(NROWS * (DDIM / 4)) / 256, 256, 0, stream>>>(x, xb, (size_t)NROWS * DDIM);
  tlogit_kernel<<<NROWS, 256, 0, stream>>>(x, w, t, lt);

  dim3 grid(NROWS / 128, VPAD / 128);  // (32, 393), row tiles fastest
  gemm_lse_kernel<<<grid, 256, 0, stream>>>(xb, wb, S);

  loss_kernel<<<1, 1024, 0, stream>>>(S, lt, out);
}

// Round 3
// 1129.284 us; speedup vs baseline: 1.0610x; 1.0610x over previous
//
#include <hip/hip_runtime.h>
#include <hip/hip_bf16.h>
#include <stdint.h>

// Problem constants (reference: N=4096, D=1024, V=50257)
#define NROWS 4096
#define DDIM  1024
#define VDIM  50257
#define VPAD  50304   // 393 * 128

typedef __bf16 bf16;
typedef __bf16 bf16x4 __attribute__((ext_vector_type(4)));
typedef __bf16 bf16x8 __attribute__((ext_vector_type(8)));
typedef float  f32x16 __attribute__((ext_vector_type(16)));

// ---- async global -> LDS, 16B per lane (dest = wave-uniform base + lane*16) ----
__device__ __forceinline__ void async_load16(const void* gsrc, const void* lds_dst) {
  __builtin_amdgcn_global_load_lds(
      (__attribute__((address_space(1))) unsigned int*)(uintptr_t)gsrc,
      (__attribute__((address_space(3))) unsigned int*)(uint32_t)(uintptr_t)lds_dst,
      16, 0, 0);
}

// ---- fp32 -> bf16 conversion (4 elems/thread); pads beyond n_src with zeros ----
__global__ __launch_bounds__(256)
void cvt_kernel(const float* __restrict__ src, bf16* __restrict__ dst, size_t n_src) {
  size_t i = ((size_t)blockIdx.x * 256 + threadIdx.x) * 4;
  float4 f = make_float4(0.f, 0.f, 0.f, 0.f);
  if (i < n_src) f = *(const float4*)(src + i);
  bf16x4 o = { (__bf16)f.x, (__bf16)f.y, (__bf16)f.z, (__bf16)f.w };
  *(bf16x4*)(dst + i) = o;
}

// ---- exact fp32 target logit: lt[n] = dot(x[n], w[target[n]]) ----
__global__ __launch_bounds__(256)
void tlogit_kernel(const float* __restrict__ x, const float* __restrict__ w,
                   const int* __restrict__ tgt, float* __restrict__ lt) {
  int n = blockIdx.x;
  int t = tgt[n];
  const float4* xr = (const float4*)(x + (size_t)n * DDIM);
  const float4* wr = (const float4*)(w + (size_t)t * DDIM);
  float4 a = xr[threadIdx.x];
  float4 b = wr[threadIdx.x];
  float s = a.x * b.x + a.y * b.y + a.z * b.z + a.w * b.w;
  #pragma unroll
  for (int m = 32; m; m >>= 1) s += __shfl_down(s, m);
  __shared__ float red[4];
  if ((threadIdx.x & 63) == 0) red[threadIdx.x >> 6] = s;
  __syncthreads();
  if (threadIdx.x == 0) lt[n] = red[0] + red[1] + red[2] + red[3];
}

// ---- fused GEMM (bf16 32x32x16 MFMA) + exp + per-row partial sum -> atomicAdd ----
// Block tile: BM=256 (x rows) x BN=128 (vocab) x BK=32. 256 threads = 4 waves in
// 2(m) x 2(n); wave tile 128x64 = 4x2 blocks of 32x32, acc = 8 x f32x16 (128 AGPR).
// Double-buffered LDS (2 x 24KB). Per iter: barrier -> ds_read all fragments ->
// [sched_barrier] -> issue next stage's global_load_lds -> [sched_barrier] -> MFMA.
// Ordering matters: the waitcnt legalizer conservatively drains vmcnt before any
// ds_read that might alias an outstanding LDS-DMA write. Reading BEFORE issuing
// the prefetch means that drain is trivially satisfied (previous stage already
// drained at the barrier), so the prefetch stays in flight through the whole
// MFMA phase and across the next barrier's arrival.
__global__ __launch_bounds__(256, 2)
void gemm_lse_kernel(const bf16* __restrict__ xb,   // [NROWS][DDIM]
                     const bf16* __restrict__ wb,   // [VPAD][DDIM] (pad rows zero)
                     float* __restrict__ S) {       // [NROWS] running sum of exp
  __shared__ __align__(16) unsigned char smem[49152];  // 2 stages x (A 16K + B 8K)

  const int tid  = threadIdx.x;
  const int wid  = tid >> 6;    // 0..3
  const int lane = tid & 63;
  const int c31  = lane & 31;
  const int h    = lane >> 5;   // 0..1

  const int m0 = blockIdx.x * 256;
  const int v0 = blockIdx.y * 128;

  const int wave_m = wid >> 1;  // 0..1
  const int wave_n = wid & 1;   // 0..1

  // Staging: LDS stage layout  A: [chunk c 0..3][row 0..255] 16B slots (16KB),
  //                            B: +16384, [c 0..3][row 0..127] (8KB).
  // Wave wid stages k-chunk c == wid: A rows t*64+lane (t=0..3), B rows t*64+lane (t=0..1).
  const bf16* gA[4];
  #pragma unroll
  for (int t = 0; t < 4; ++t)
    gA[t] = xb + (size_t)(m0 + t * 64 + lane) * DDIM + wid * 8;
  const bf16* gB[2];
  #pragma unroll
  for (int t = 0; t < 2; ++t)
    gB[t] = wb + (size_t)(v0 + t * 64 + lane) * DDIM + wid * 8;

  uint32_t dA[4], dB[2];
  #pragma unroll
  for (int t = 0; t < 4; ++t) dA[t] = (uint32_t)(wid * 256 + t * 64) * 16u;
  #pragma unroll
  for (int t = 0; t < 2; ++t) dB[t] = 16384u + (uint32_t)(wid * 128 + t * 64) * 16u;

  // Fragment offsets. 32x32x16 A-operand: A[m=lane&31][k=(lane>>5)*8+j]; k-chunk
  // index = kk*2 + h. B symmetric (weights are row-major [n][k] = B^T).
  uint32_t aoff[4][2], boff[2][2];
  #pragma unroll
  for (int mi = 0; mi < 4; ++mi)
    #pragma unroll
    for (int kk = 0; kk < 2; ++kk)
      aoff[mi][kk] = (uint32_t)((kk * 2 + h) * 256 + wave_m * 128 + mi * 32 + c31) * 16u;
  #pragma unroll
  for (int ni = 0; ni < 2; ++ni)
    #pragma unroll
    for (int kk = 0; kk < 2; ++kk)
      boff[ni][kk] = 16384u + (uint32_t)((kk * 2 + h) * 128 + wave_n * 64 + ni * 32 + c31) * 16u;

  f32x16 acc[4][2] = {};

  // Prologue: stage 0 -> buffer 0.
  #pragma unroll
  for (int t = 0; t < 4; ++t) async_load16(gA[t], smem + dA[t]);
  #pragma unroll
  for (int t = 0; t < 2; ++t) async_load16(gB[t], smem + dB[t]);

  uint32_t p = 0;
  for (int k0 = 0; k0 < DDIM; k0 += 32) {
    __syncthreads();  // stage p's loads have been in flight for a full MFMA phase
    const uint32_t sb = p * 24576u;

    bf16x8 af[4][2], bfv[2][2];
    #pragma unroll
    for (int mi = 0; mi < 4; ++mi)
      #pragma unroll
      for (int kk = 0; kk < 2; ++kk)
        af[mi][kk] = *(const bf16x8*)(smem + sb + aoff[mi][kk]);
    #pragma unroll
    for (int ni = 0; ni < 2; ++ni)
      #pragma unroll
      for (int kk = 0; kk < 2; ++kk)
        bfv[ni][kk] = *(const bf16x8*)(smem + sb + boff[ni][kk]);

    __builtin_amdgcn_sched_barrier(0);  // keep prefetch BELOW the ds_reads

    if (k0 + 32 < DDIM) {
      const uint32_t nb = (p ^ 1) * 24576u;
      #pragma unroll
      for (int t = 0; t < 4; ++t) async_load16(gA[t] + k0 + 32, smem + nb + dA[t]);
      #pragma unroll
      for (int t = 0; t < 2; ++t) async_load16(gB[t] + k0 + 32, smem + nb + dB[t]);
    }

    __builtin_amdgcn_sched_barrier(0);  // keep prefetch ABOVE the MFMA phase

    #pragma unroll
    for (int kk = 0; kk < 2; ++kk)
      #pragma unroll
      for (int mi = 0; mi < 4; ++mi)
        #pragma unroll
        for (int ni = 0; ni < 2; ++ni)
          acc[mi][ni] = __builtin_amdgcn_mfma_f32_32x32x16_bf16(
              af[mi][kk], bfv[ni][kk], acc[mi][ni], 0, 0, 0);

    p ^= 1;
  }

  // Epilogue. 32x32 C/D layout: col = lane&31, row = (reg&3) + 8*(reg>>2) + 4*(lane>>5).
  #pragma unroll
  for (int mi = 0; mi < 4; ++mi) {
    #pragma unroll
    for (int r = 0; r < 16; ++r) {
      float pacc = 0.f;
      #pragma unroll
      for (int ni = 0; ni < 2; ++ni) {
        int v = v0 + wave_n * 64 + ni * 32 + c31;
        float e = __expf(acc[mi][ni][r]);
        pacc += (v < VDIM) ? e : 0.f;   // mask vocab pad
      }
      pacc += __shfl_xor(pacc, 16);
      pacc += __shfl_xor(pacc, 8);
      pacc += __shfl_xor(pacc, 4);
      pacc += __shfl_xor(pacc, 2);
      pacc += __shfl_xor(pacc, 1);
      if (c31 == 0) {
        int row = m0 + wave_m * 128 + mi * 32 + (r & 3) + 8 * (r >> 2) + 4 * h;
        atomicAdd(&S[row], pacc);
      }
    }
  }
}

// ---- final: loss = mean(log(S[n]) - lt[n]) ----
__global__ __launch_bounds__(1024)
void loss_kernel(const float* __restrict__ S, const float* __restrict__ lt,
                 float* __restrict__ out) {
  float s = 0.f;
  for (int n = threadIdx.x; n < NROWS; n += 1024)
    s += logf(S[n]) - lt[n];
  #pragma unroll
  for (int m = 32; m; m >>= 1) s += __shfl_down(s, m);
  __shared__ float red[16];
  if ((threadIdx.x & 63) == 0) red[threadIdx.x >> 6] = s;
  __syncthreads();
  if (threadIdx.x == 0) {
    float t = 0.f;
    #pragma unroll
    for (int i = 0; i < 16; ++i) t += red[i];
    out[0] = t / (float)NROWS;
  }
}

extern "C" void kernel_launch(void* const* d_in, const int* in_sizes, int n_in,
                              void* d_out, int out_size, void* d_ws, size_t ws_size,
                              hipStream_t stream) {
  const float* x = (const float*)d_in[0];   // [4096,1024] fp32
  const float* w = (const float*)d_in[1];   // [50257,1024] fp32
  const int*   t = (const int*)d_in[2];     // [4096] int
  float* out = (float*)d_out;

  char* ws = (char*)d_ws;
  const size_t wb_bytes = (size_t)VPAD * DDIM * sizeof(bf16);   // 103.0 MB
  const size_t xb_bytes = (size_t)NROWS * DDIM * sizeof(bf16);  //   8.4 MB
  bf16*  wb = (bf16*)ws;
  bf16*  xb = (bf16*)(ws + wb_bytes);
  float* S  = (float*)(ws + wb_bytes + xb_bytes);
  float* lt = S + NROWS;

  if (ws_size < wb_bytes + xb_bytes + 2 * NROWS * sizeof(float)) return; // fail loud

  hipMemsetAsync(S, 0, NROWS * sizeof(float), stream);
  cvt_kernel<<<(VPAD * (DDIM / 4)) / 256, 256, 0, stream>>>(w, wb, (size_t)VDIM * DDIM);
  cvt_kernel<<<(NROWS * (DDIM / 4)) / 256, 256, 0, stream>>>(x, xb, (size_t)NROWS * DDIM);
  tlogit_kernel<<<NROWS, 256, 0, stream>>>(x, w, t, lt);

  dim3 grid(NROWS / 256, VPAD / 128);  // (16, 393)
  gemm_lse_kernel<<<grid, 256, 0, stream>>>(xb, wb, S);

  loss_kernel<<<1, 1024, 0, stream>>>(S, lt, out);
}

// Round 4
// 973.013 us; speedup vs baseline: 1.2314x; 1.1606x over previous
//
#include <hip/hip_runtime.h>
#include <hip/hip_bf16.h>
#include <stdint.h>

// Problem constants (reference: N=4096, D=1024, V=50257)
#define NROWS 4096
#define DDIM  1024
#define VDIM  50257
#define VPAD  50304   // 393 * 128

typedef __bf16 bf16;
typedef __bf16 bf16x4 __attribute__((ext_vector_type(4)));
typedef __bf16 bf16x8 __attribute__((ext_vector_type(8)));
typedef float  f32x16 __attribute__((ext_vector_type(16)));

// ---- async global -> LDS, 16B per lane (dest = wave-uniform base + lane*16) ----
__device__ __forceinline__ void async_load16(const void* gsrc, const void* lds_dst) {
  __builtin_amdgcn_global_load_lds(
      (__attribute__((address_space(1))) unsigned int*)(uintptr_t)gsrc,
      (__attribute__((address_space(3))) unsigned int*)(uint32_t)(uintptr_t)lds_dst,
      16, 0, 0);
}

// ---- fp32 -> bf16 conversion (8 elems/thread); pads beyond n_src with zeros ----
__global__ __launch_bounds__(256)
void cvt_kernel(const float* __restrict__ src, bf16* __restrict__ dst, size_t n_src) {
  size_t i = ((size_t)blockIdx.x * 256 + threadIdx.x) * 8;
  float4 f0 = make_float4(0.f, 0.f, 0.f, 0.f), f1 = f0;
  if (i < n_src) { f0 = *(const float4*)(src + i); f1 = *(const float4*)(src + i + 4); }
  bf16x8 o = { (__bf16)f0.x, (__bf16)f0.y, (__bf16)f0.z, (__bf16)f0.w,
               (__bf16)f1.x, (__bf16)f1.y, (__bf16)f1.z, (__bf16)f1.w };
  *(bf16x8*)(dst + i) = o;
}

// ---- exact fp32 target logit: lt[n] = dot(x[n], w[target[n]]) ----
__global__ __launch_bounds__(256)
void tlogit_kernel(const float* __restrict__ x, const float* __restrict__ w,
                   const int* __restrict__ tgt, float* __restrict__ lt) {
  int n = blockIdx.x;
  int t = tgt[n];
  const float4* xr = (const float4*)(x + (size_t)n * DDIM);
  const float4* wr = (const float4*)(w + (size_t)t * DDIM);
  float4 a = xr[threadIdx.x];
  float4 b = wr[threadIdx.x];
  float s = a.x * b.x + a.y * b.y + a.z * b.z + a.w * b.w;
  #pragma unroll
  for (int m = 32; m; m >>= 1) s += __shfl_down(s, m);
  __shared__ float red[4];
  if ((threadIdx.x & 63) == 0) red[threadIdx.x >> 6] = s;
  __syncthreads();
  if (threadIdx.x == 0) lt[n] = red[0] + red[1] + red[2] + red[3];
}

// ---- fused GEMM (bf16 32x32x16 MFMA) + exp + per-row partial sum -> atomicAdd ----
// Block tile: BM=256 x BN=128 x BK=32. 256 threads = 4 waves (2m x 2n); wave tile
// 128x64. COALESCED LDS-DMA staging: each global_load_lds covers 16 rows x 64B
// (lane i -> row i>>2, 16B chunk i&3): every 64B cacheline fully consumed
// (16 segments/inst, vs 64 lines/inst in the previous row-strided layout).
// Stage layout (forced by dest = base + lane*16): row-major, row stride 64B.
// To kill the resulting 16-way fragment-read bank conflicts, the k-chunk is
// XOR-swizzled per row: slot (r, j) holds global chunk j ^ ((r>>1)&3), applied
// on the global address (free). Fragment reads then hit the 8-cyc b128 floor.
__global__ __launch_bounds__(256, 2)
void gemm_lse_kernel(const bf16* __restrict__ xb,   // [NROWS][DDIM]
                     const bf16* __restrict__ wb,   // [VPAD][DDIM] (pad rows zero)
                     float* __restrict__ S) {       // [NROWS] running sum of exp
  __shared__ __align__(16) unsigned char smem[49152];  // 2 stages x (A 16K + B 8K)

  const int tid  = threadIdx.x;
  const int wid  = tid >> 6;    // 0..3
  const int lane = tid & 63;
  const int c31  = lane & 31;
  const int h    = lane >> 5;   // 0..1

  const int m0 = blockIdx.x * 256;
  const int v0 = blockIdx.y * 128;

  const int wave_m = wid >> 1;  // 0..1
  const int wave_n = wid & 1;   // 0..1

  // Staging: A = 16 insts of 16 rows x 64B (16KB); B = 8 insts (8KB, base 16384).
  // Wave wid: A insts wid*4..wid*4+3, B insts wid*2..wid*2+1.
  const int lrow = lane >> 2;        // 0..15 row within inst
  const int lchk = lane & 3;         // 16B chunk slot within row
  const bf16* gA[4]; uint32_t dA[4];
  #pragma unroll
  for (int a = 0; a < 4; ++a) {
    int t = wid * 4 + a;
    int r = t * 16 + lrow;
    int col = (lchk ^ ((r >> 1) & 3)) * 8;   // swizzled global k-chunk (elems)
    gA[a] = xb + (size_t)(m0 + r) * DDIM + col;
    dA[a] = (uint32_t)(t * 1024 + lane * 16);
  }
  const bf16* gB[2]; uint32_t dB[2];
  #pragma unroll
  for (int b = 0; b < 2; ++b) {
    int t = wid * 2 + b;
    int r = t * 16 + lrow;
    int col = (lchk ^ ((r >> 1) & 3)) * 8;
    gB[b] = wb + (size_t)(v0 + r) * DDIM + col;
    dB[b] = (uint32_t)(16384 + t * 1024 + lane * 16);
  }

  // Fragment offsets. A[m][k16] at m*64 + (k16 ^ ((m>>1)&3))*16; k16 = kk*2+h.
  uint32_t aoff[4][2], boff[2][2];
  #pragma unroll
  for (int mi = 0; mi < 4; ++mi)
    #pragma unroll
    for (int kk = 0; kk < 2; ++kk) {
      int m = wave_m * 128 + mi * 32 + c31;
      aoff[mi][kk] = (uint32_t)(m * 64 + (((kk * 2 + h) ^ ((m >> 1) & 3)) * 16));
    }
  #pragma unroll
  for (int ni = 0; ni < 2; ++ni)
    #pragma unroll
    for (int kk = 0; kk < 2; ++kk) {
      int n = wave_n * 64 + ni * 32 + c31;
      boff[ni][kk] = (uint32_t)(16384 + n * 64 + (((kk * 2 + h) ^ ((n >> 1) & 3)) * 16));
    }

  f32x16 acc[4][2] = {};

  // Prologue: stage 0 -> buffer 0.
  #pragma unroll
  for (int a = 0; a < 4; ++a) async_load16(gA[a], smem + dA[a]);
  #pragma unroll
  for (int b = 0; b < 2; ++b) async_load16(gB[b], smem + dB[b]);

  uint32_t p = 0;
  for (int k0 = 0; k0 < DDIM; k0 += 32) {
    __syncthreads();  // stage p's loads drained here (issued one full phase ago)
    const uint32_t sb = p * 24576u;

    bf16x8 af[4][2], bfv[2][2];
    #pragma unroll
    for (int mi = 0; mi < 4; ++mi)
      #pragma unroll
      for (int kk = 0; kk < 2; ++kk)
        af[mi][kk] = *(const bf16x8*)(smem + sb + aoff[mi][kk]);
    #pragma unroll
    for (int ni = 0; ni < 2; ++ni)
      #pragma unroll
      for (int kk = 0; kk < 2; ++kk)
        bfv[ni][kk] = *(const bf16x8*)(smem + sb + boff[ni][kk]);

    __builtin_amdgcn_sched_barrier(0);  // prefetch stays BELOW the ds_reads

    if (k0 + 32 < DDIM) {
      const uint32_t nb = (p ^ 1) * 24576u;
      #pragma unroll
      for (int a = 0; a < 4; ++a) async_load16(gA[a] + k0 + 32, smem + nb + dA[a]);
      #pragma unroll
      for (int b = 0; b < 2; ++b) async_load16(gB[b] + k0 + 32, smem + nb + dB[b]);
    }

    __builtin_amdgcn_sched_barrier(0);  // prefetch stays ABOVE the MFMA phase

    #pragma unroll
    for (int kk = 0; kk < 2; ++kk)
      #pragma unroll
      for (int mi = 0; mi < 4; ++mi)
        #pragma unroll
        for (int ni = 0; ni < 2; ++ni)
          acc[mi][ni] = __builtin_amdgcn_mfma_f32_32x32x16_bf16(
              af[mi][kk], bfv[ni][kk], acc[mi][ni], 0, 0, 0);

    p ^= 1;
  }

  // Epilogue. 32x32 C/D layout: col = lane&31, row = (reg&3) + 8*(reg>>2) + 4*(lane>>5).
  #pragma unroll
  for (int mi = 0; mi < 4; ++mi) {
    #pragma unroll
    for (int r = 0; r < 16; ++r) {
      float pacc = 0.f;
      #pragma unroll
      for (int ni = 0; ni < 2; ++ni) {
        int v = v0 + wave_n * 64 + ni * 32 + c31;
        float e = __expf(acc[mi][ni][r]);
        pacc += (v < VDIM) ? e : 0.f;   // mask vocab pad
      }
      pacc += __shfl_xor(pacc, 16);
      pacc += __shfl_xor(pacc, 8);
      pacc += __shfl_xor(pacc, 4);
      pacc += __shfl_xor(pacc, 2);
      pacc += __shfl_xor(pacc, 1);
      if (c31 == 0) {
        int row = m0 + wave_m * 128 + mi * 32 + (r & 3) + 8 * (r >> 2) + 4 * h;
        atomicAdd(&S[row], pacc);
      }
    }
  }
}

// ---- final: loss = mean(log(S[n]) - lt[n]) ----
__global__ __launch_bounds__(1024)
void loss_kernel(const float* __restrict__ S, const float* __restrict__ lt,
                 float* __restrict__ out) {
  float s = 0.f;
  for (int n = threadIdx.x; n < NROWS; n += 1024)
    s += logf(S[n]) - lt[n];
  #pragma unroll
  for (int m = 32; m; m >>= 1) s += __shfl_down(s, m);
  __shared__ float red[16];
  if ((threadIdx.x & 63) == 0) red[threadIdx.x >> 6] = s;
  __syncthreads();
  if (threadIdx.x == 0) {
    float t = 0.f;
    #pragma unroll
    for (int i = 0; i < 16; ++i) t += red[i];
    out[0] = t / (float)NROWS;
  }
}

extern "C" void kernel_launch(void* const* d_in, const int* in_sizes, int n_in,
                              void* d_out, int out_size, void* d_ws, size_t ws_size,
                              hipStream_t stream) {
  const float* x = (const float*)d_in[0];   // [4096,1024] fp32
  const float* w = (const float*)d_in[1];   // [50257,1024] fp32
  const int*   t = (const int*)d_in[2];     // [4096] int
  float* out = (float*)d_out;

  char* ws = (char*)d_ws;
  const size_t wb_bytes = (size_t)VPAD * DDIM * sizeof(bf16);   // 103.0 MB
  const size_t xb_bytes = (size_t)NROWS * DDIM * sizeof(bf16);  //   8.4 MB
  bf16*  wb = (bf16*)ws;
  bf16*  xb = (bf16*)(ws + wb_bytes);
  float* S  = (float*)(ws + wb_bytes + xb_bytes);
  float* lt = S + NROWS;

  if (ws_size < wb_bytes + xb_bytes + 2 * NROWS * sizeof(float)) return; // fail loud

  hipMemsetAsync(S, 0, NROWS * sizeof(float), stream);
  cvt_kernel<<<(VPAD * (DDIM / 8)) / 256, 256, 0, stream>>>(w, wb, (size_t)VDIM * DDIM);
  cvt_kernel<<<(NROWS * (DDIM / 8)) / 256, 256, 0, stream>>>(x, xb, (size_t)NROWS * DDIM);
  tlogit_kernel<<<NROWS, 256, 0, stream>>>(x, w, t, lt);

  dim3 grid(NROWS / 256, VPAD / 128);  // (16, 393)
  gemm_lse_kernel<<<grid, 256, 0, stream>>>(xb, wb, S);

  loss_kernel<<<1, 1024, 0, stream>>>(S, lt, out);
}

// Round 5
// 815.211 us; speedup vs baseline: 1.4697x; 1.1936x over previous
//
#include <hip/hip_runtime.h>
#include <hip/hip_bf16.h>
#include <stdint.h>

// Problem constants (reference: N=4096, D=1024, V=50257)
#define NROWS 4096
#define DDIM  1024
#define VDIM  50257
#define VPAD  50304   // 393 * 128

// LDS geometry: row-major, pitch 80 B (64 B data + 16 B pad; multiple of 16 for
// aligned b128; pitch/8=10 gives max 2-way phase aliasing on reads AND writes
// under the 16-lane x 8B phase model deduced from r3(0-conflict)/r4(conflict)).
#define PITCH   80
#define B_BASE  20480            // A: 256*80
#define STAGE   30720            // + B: 128*80
typedef __bf16 bf16;
typedef __bf16 bf16x4 __attribute__((ext_vector_type(4)));
typedef __bf16 bf16x8 __attribute__((ext_vector_type(8)));
typedef float  f32x16 __attribute__((ext_vector_type(16)));

// ---- fp32 -> bf16 conversion (8 elems/thread); pads beyond n_src with zeros ----
__global__ __launch_bounds__(256)
void cvt_kernel(const float* __restrict__ src, bf16* __restrict__ dst, size_t n_src) {
  size_t i = ((size_t)blockIdx.x * 256 + threadIdx.x) * 8;
  float4 f0 = make_float4(0.f, 0.f, 0.f, 0.f), f1 = f0;
  if (i < n_src) { f0 = *(const float4*)(src + i); f1 = *(const float4*)(src + i + 4); }
  bf16x8 o = { (__bf16)f0.x, (__bf16)f0.y, (__bf16)f0.z, (__bf16)f0.w,
               (__bf16)f1.x, (__bf16)f1.y, (__bf16)f1.z, (__bf16)f1.w };
  *(bf16x8*)(dst + i) = o;
}

// ---- exact fp32 target logit: lt[n] = dot(x[n], w[target[n]]) ----
__global__ __launch_bounds__(256)
void tlogit_kernel(const float* __restrict__ x, const float* __restrict__ w,
                   const int* __restrict__ tgt, float* __restrict__ lt) {
  int n = blockIdx.x;
  int t = tgt[n];
  const float4* xr = (const float4*)(x + (size_t)n * DDIM);
  const float4* wr = (const float4*)(w + (size_t)t * DDIM);
  float4 a = xr[threadIdx.x];
  float4 b = wr[threadIdx.x];
  float s = a.x * b.x + a.y * b.y + a.z * b.z + a.w * b.w;
  #pragma unroll
  for (int m = 32; m; m >>= 1) s += __shfl_down(s, m);
  __shared__ float red[4];
  if ((threadIdx.x & 63) == 0) red[threadIdx.x >> 6] = s;
  __syncthreads();
  if (threadIdx.x == 0) lt[n] = red[0] + red[1] + red[2] + red[3];
}

// ---- fused GEMM (bf16 32x32x16 MFMA) + exp + per-row partial sum -> atomicAdd ----
// Block tile: BM=256 x BN=128 x BK=32; 4 waves (2m x 2n), wave tile 128x64.
// REG-STAGED distance-2 pipeline (no global_load_lds -> no vmcnt(0) drain at
// barriers): iter k does  ds_read frags(k) | wait+ds_write stage(k+1) |
// issue global loads stage(k+2) -> regs | MFMA(k) | barrier.
// The barrier only needs lgkmcnt (LDS) drained; the stage-(k+2) global loads
// stay in flight across it and are waited (by register dependence) only at
// iter k+1's ds_write -- a full iteration later.
__global__ __launch_bounds__(256, 2)
void gemm_lse_kernel(const bf16* __restrict__ xb,   // [NROWS][DDIM]
                     const bf16* __restrict__ wb,   // [VPAD][DDIM] (pad rows zero)
                     float* __restrict__ S) {       // [NROWS] running sum of exp
  __shared__ __align__(16) unsigned char smem[2 * STAGE];  // 60 KB -> 2 blocks/CU

  const int tid  = threadIdx.x;
  const int wid  = tid >> 6;    // 0..3
  const int lane = tid & 63;
  const int c31  = lane & 31;
  const int h    = lane >> 5;   // 0..1

  const int m0 = blockIdx.x * 256;
  const int v0 = blockIdx.y * 128;
  const int wave_m = wid >> 1;  // 0..1
  const int wave_n = wid & 1;   // 0..1

  // Global staging: per inst 16 rows x 64B contiguous (lane -> row lane>>2,
  // 16B chunk lane&3): 16 fully-consumed cachelines per inst.
  const int lr = lane >> 2;   // 0..15
  const int lc = lane & 3;    // 0..3
  const bf16* gA[4]; uint32_t wAo[4];
  #pragma unroll
  for (int a = 0; a < 4; ++a) {
    int r = (wid * 4 + a) * 16 + lr;               // 0..255
    gA[a]  = xb + (size_t)(m0 + r) * DDIM + lc * 8;
    wAo[a] = (uint32_t)(r * PITCH + lc * 16);
  }
  const bf16* gB[2]; uint32_t wBo[2];
  #pragma unroll
  for (int b = 0; b < 2; ++b) {
    int r = (wid * 2 + b) * 16 + lr;               // 0..127
    gB[b]  = wb + (size_t)(v0 + r) * DDIM + lc * 8;
    wBo[b] = (uint32_t)(B_BASE + r * PITCH + lc * 16);
  }

  // Fragment read offsets: A[m = base+c31][k16 = kk*2+h] at m*PITCH + k16*16.
  uint32_t aoff[4][2], boff[2][2];
  #pragma unroll
  for (int mi = 0; mi < 4; ++mi)
    #pragma unroll
    for (int kk = 0; kk < 2; ++kk)
      aoff[mi][kk] = (uint32_t)((wave_m * 128 + mi * 32 + c31) * PITCH + (kk * 2 + h) * 16);
  #pragma unroll
  for (int ni = 0; ni < 2; ++ni)
    #pragma unroll
    for (int kk = 0; kk < 2; ++kk)
      boff[ni][kk] = (uint32_t)(B_BASE + (wave_n * 64 + ni * 32 + c31) * PITCH + (kk * 2 + h) * 16);

  f32x16 acc[4][2] = {};
  bf16x8 rA[4], rB[2];

  // Prologue: load+write stage 0, issue stage 1.
  #pragma unroll
  for (int a = 0; a < 4; ++a) rA[a] = *(const bf16x8*)gA[a];
  #pragma unroll
  for (int b = 0; b < 2; ++b) rB[b] = *(const bf16x8*)gB[b];
  #pragma unroll
  for (int a = 0; a < 4; ++a) *(bf16x8*)(smem + wAo[a]) = rA[a];
  #pragma unroll
  for (int b = 0; b < 2; ++b) *(bf16x8*)(smem + wBo[b]) = rB[b];
  #pragma unroll
  for (int a = 0; a < 4; ++a) rA[a] = *(const bf16x8*)(gA[a] + 32);
  #pragma unroll
  for (int b = 0; b < 2; ++b) rB[b] = *(const bf16x8*)(gB[b] + 32);
  __syncthreads();

  #pragma unroll 2
  for (int k = 0; k < 32; ++k) {
    const uint32_t sb = (uint32_t)(k & 1) * STAGE;
    const uint32_t nb = STAGE - sb;
    #pragma unroll
    for (int kk = 0; kk < 2; ++kk) {
      bf16x8 af[4], bfv[2];
      #pragma unroll
      for (int mi = 0; mi < 4; ++mi) af[mi]  = *(const bf16x8*)(smem + sb + aoff[mi][kk]);
      #pragma unroll
      for (int ni = 0; ni < 2; ++ni) bfv[ni] = *(const bf16x8*)(smem + sb + boff[ni][kk]);
      if (kk == 0) {
        __builtin_amdgcn_sched_barrier(0);
        if (k + 1 < 32) {  // ds_write stage k+1 (waits its loads via reg dep: vmcnt)
          #pragma unroll
          for (int a = 0; a < 4; ++a) *(bf16x8*)(smem + nb + wAo[a]) = rA[a];
          #pragma unroll
          for (int b = 0; b < 2; ++b) *(bf16x8*)(smem + nb + wBo[b]) = rB[b];
        }
        if (k + 2 < 32) {  // issue stage k+2 loads (in flight across next barrier)
          #pragma unroll
          for (int a = 0; a < 4; ++a) rA[a] = *(const bf16x8*)(gA[a] + (k + 2) * 32);
          #pragma unroll
          for (int b = 0; b < 2; ++b) rB[b] = *(const bf16x8*)(gB[b] + (k + 2) * 32);
        }
        __builtin_amdgcn_sched_barrier(0);
      }
      #pragma unroll
      for (int mi = 0; mi < 4; ++mi)
        #pragma unroll
        for (int ni = 0; ni < 2; ++ni)
          acc[mi][ni] = __builtin_amdgcn_mfma_f32_32x32x16_bf16(
              af[mi], bfv[ni], acc[mi][ni], 0, 0, 0);
    }
    __syncthreads();
  }

  // Epilogue. 32x32 C/D layout: col = lane&31, row = (reg&3) + 8*(reg>>2) + 4*(lane>>5).
  #pragma unroll
  for (int mi = 0; mi < 4; ++mi) {
    #pragma unroll
    for (int r = 0; r < 16; ++r) {
      float pacc = 0.f;
      #pragma unroll
      for (int ni = 0; ni < 2; ++ni) {
        int v = v0 + wave_n * 64 + ni * 32 + c31;
        float e = __expf(acc[mi][ni][r]);
        pacc += (v < VDIM) ? e : 0.f;   // mask vocab pad
      }
      pacc += __shfl_xor(pacc, 16);
      pacc += __shfl_xor(pacc, 8);
      pacc += __shfl_xor(pacc, 4);
      pacc += __shfl_xor(pacc, 2);
      pacc += __shfl_xor(pacc, 1);
      if (c31 == 0) {
        int row = m0 + wave_m * 128 + mi * 32 + (r & 3) + 8 * (r >> 2) + 4 * h;
        atomicAdd(&S[row], pacc);
      }
    }
  }
}

// ---- final: loss = mean(log(S[n]) - lt[n]) ----
__global__ __launch_bounds__(1024)
void loss_kernel(const float* __restrict__ S, const float* __restrict__ lt,
                 float* __restrict__ out) {
  float s = 0.f;
  for (int n = threadIdx.x; n < NROWS; n += 1024)
    s += logf(S[n]) - lt[n];
  #pragma unroll
  for (int m = 32; m; m >>= 1) s += __shfl_down(s, m);
  __shared__ float red[16];
  if ((threadIdx.x & 63) == 0) red[threadIdx.x >> 6] = s;
  __syncthreads();
  if (threadIdx.x == 0) {
    float t = 0.f;
    #pragma unroll
    for (int i = 0; i < 16; ++i) t += red[i];
    out[0] = t / (float)NROWS;
  }
}

extern "C" void kernel_launch(void* const* d_in, const int* in_sizes, int n_in,
                              void* d_out, int out_size, void* d_ws, size_t ws_size,
                              hipStream_t stream) {
  const float* x = (const float*)d_in[0];   // [4096,1024] fp32
  const float* w = (const float*)d_in[1];   // [50257,1024] fp32
  const int*   t = (const int*)d_in[2];     // [4096] int
  float* out = (float*)d_out;

  char* ws = (char*)d_ws;
  const size_t wb_bytes = (size_t)VPAD * DDIM * sizeof(bf16);   // 103.0 MB
  const size_t xb_bytes = (size_t)NROWS * DDIM * sizeof(bf16);  //   8.4 MB
  bf16*  wb = (bf16*)ws;
  bf16*  xb = (bf16*)(ws + wb_bytes);
  float* S  = (float*)(ws + wb_bytes + xb_bytes);
  float* lt = S + NROWS;

  if (ws_size < wb_bytes + xb_bytes + 2 * NROWS * sizeof(float)) return; // fail loud

  hipMemsetAsync(S, 0, NROWS * sizeof(float), stream);
  cvt_kernel<<<(VPAD * (DDIM / 8)) / 256, 256, 0, stream>>>(w, wb, (size_t)VDIM * DDIM);
  cvt_kernel<<<(NROWS * (DDIM / 8)) / 256, 256, 0, stream>>>(x, xb, (size_t)NROWS * DDIM);
  tlogit_kernel<<<NROWS, 256, 0, stream>>>(x, w, t, lt);

  dim3 grid(NROWS / 256, VPAD / 128);  // (16, 393)
  gemm_lse_kernel<<<grid, 256, 0, stream>>>(xb, wb, S);

  loss_kernel<<<1, 1024, 0, stream>>>(S, lt, out);
}

// Round 6
// 802.319 us; speedup vs baseline: 1.4933x; 1.0161x over previous
//
#include <hip/hip_runtime.h>
#include <hip/hip_bf16.h>
#include <stdint.h>

// Problem constants (reference: N=4096, D=1024, V=50257)
#define NROWS 4096
#define DDIM  1024
#define VDIM  50257
#define VPAD  50304   // 393 * 128
#define NVT   393     // v-tiles
#define NMT   16      // m-tiles (256 rows each)

// fp8 scales: w*64, x*8 -> logits scaled by 512 (exact pow2, descale pre-exp)
#define DESCALE (1.0f / 512.0f)

// LDS stage: A 256 rows + B 128 rows, 64B data/row (fp8 K=64), pitch 80.
// Row content order: [h (0..1)][t (0..3)] 8B granules, where the global k-byte
// granule q (k = q*8..q*8+7) has (t = q>>1, h = q&1). One b128 frag-read at
// h*32 + j*16 returns fragments (t=2j, t=2j+1) for that lane's h.
#define PITCH  80
#define B_BASE 20480             // 256*80
#define STAGE  30720             // + 128*80

typedef long  i64;
typedef i64   i64x2 __attribute__((ext_vector_type(2)));
typedef float f32x16 __attribute__((ext_vector_type(16)));

// ---- fp32 -> fp8 e4m3 (OCP on gfx950), 16 elems/thread, scaled; zero pad ----
__global__ __launch_bounds__(256)
void cvtq_kernel(const float* __restrict__ src, uint32_t* __restrict__ dst,
                 size_t n_src, float scale) {
  size_t i = ((size_t)blockIdx.x * 256 + threadIdx.x) * 16;
  uint32_t o[4] = {0u, 0u, 0u, 0u};
  if (i < n_src) {   // n_src is a multiple of 16 -> all-or-nothing is exact
    const float4* s = (const float4*)(src + i);
    #pragma unroll
    for (int d = 0; d < 4; ++d) {
      float4 f = s[d];
      uint32_t v = 0;
      v = __builtin_amdgcn_cvt_pk_fp8_f32(f.x * scale, f.y * scale, v, false);
      v = __builtin_amdgcn_cvt_pk_fp8_f32(f.z * scale, f.w * scale, v, true);
      o[d] = v;
    }
  }
  *(uint4*)(dst + i / 4) = make_uint4(o[0], o[1], o[2], o[3]);
}

// ---- exact fp32 target logit: lt[n] = dot(x[n], w[target[n]]) ----
__global__ __launch_bounds__(256)
void tlogit_kernel(const float* __restrict__ x, const float* __restrict__ w,
                   const int* __restrict__ tgt, float* __restrict__ lt) {
  int n = blockIdx.x;
  int t = tgt[n];
  const float4* xr = (const float4*)(x + (size_t)n * DDIM);
  const float4* wr = (const float4*)(w + (size_t)t * DDIM);
  float4 a = xr[threadIdx.x];
  float4 b = wr[threadIdx.x];
  float s = a.x * b.x + a.y * b.y + a.z * b.z + a.w * b.w;
  #pragma unroll
  for (int m = 32; m; m >>= 1) s += __shfl_down(s, m);
  __shared__ float red[4];
  if ((threadIdx.x & 63) == 0) red[threadIdx.x >> 6] = s;
  __syncthreads();
  if (threadIdx.x == 0) lt[n] = red[0] + red[1] + red[2] + red[3];
}

// ---- fused fp8 GEMM (32x32x16 fp8_fp8) + exp + row-sum -> atomicAdd S ----
// Block 256x128xBK64, 4 waves (2m x 2n), wave tile 128x64. Reg-staged
// distance-2 pipeline (r5 structure). XCD swizzle: the 16 m-tiles of one
// v-slab share flat&7 -> one XCD streams each weight slab once; fp8 A (4MB
// total) becomes L2-resident per XCD.
__global__ __launch_bounds__(256, 2)
void gemm_lse_kernel(const uint8_t* __restrict__ xq,   // [NROWS][DDIM] fp8
                     const uint8_t* __restrict__ wq,   // [VPAD][DDIM] fp8 (pad 0)
                     float* __restrict__ S) {          // [NROWS] sum of exp
  __shared__ __align__(16) unsigned char smem[2 * STAGE];  // 60 KB

  const int tid  = threadIdx.x;
  const int wid  = tid >> 6;    // 0..3
  const int lane = tid & 63;
  const int c31  = lane & 31;
  const int h    = lane >> 5;   // 0..1

  // Block remap: grid (16,393) -> flat; same-v blocks share flat&7 (same XCD
  // under id%8 round-robin). Tail 16 blocks -> v-tile 392.
  const int flat = blockIdx.x + blockIdx.y * 16;
  int bm, vt;
  if (flat >= (NVT - 1) * 16) { vt = NVT - 1; bm = flat - (NVT - 1) * 16; }
  else { vt = (flat >> 7) * 8 + (flat & 7); bm = (flat >> 3) & 15; }
  const int m0 = bm * 256;
  const int v0 = vt * 128;

  const int wave_m = wid >> 1;  // 0..1
  const int wave_n = wid & 1;   // 0..1

  // Staging: per inst 16 rows x 64B contiguous (lane -> row lane>>2, 16B piece
  // lane&3). Piece lc = granules (t=lc,h=0),(t=lc,h=1) -> LDS at lc*8 and +32.
  const int lr = lane >> 2;   // 0..15
  const int lc = lane & 3;    // 0..3
  const uint8_t* gA[4]; uint32_t wAo[4];
  #pragma unroll
  for (int a = 0; a < 4; ++a) {
    int r = (wid * 4 + a) * 16 + lr;                 // 0..255
    gA[a]  = xq + (size_t)(m0 + r) * DDIM + lc * 16;
    wAo[a] = (uint32_t)(r * PITCH + lc * 8);
  }
  const uint8_t* gB[2]; uint32_t wBo[2];
  #pragma unroll
  for (int b = 0; b < 2; ++b) {
    int r = (wid * 2 + b) * 16 + lr;                 // 0..127
    gB[b]  = wq + (size_t)(v0 + r) * DDIM + lc * 16;
    wBo[b] = (uint32_t)(B_BASE + r * PITCH + lc * 8);
  }

  // Fragment read offsets: row m, section h, pair j -> frags t=2j, 2j+1.
  uint32_t aoff[4][2], boff[2][2];
  #pragma unroll
  for (int mi = 0; mi < 4; ++mi)
    #pragma unroll
    for (int j = 0; j < 2; ++j)
      aoff[mi][j] = (uint32_t)((wave_m * 128 + mi * 32 + c31) * PITCH + h * 32 + j * 16);
  #pragma unroll
  for (int ni = 0; ni < 2; ++ni)
    #pragma unroll
    for (int j = 0; j < 2; ++j)
      boff[ni][j] = (uint32_t)(B_BASE + (wave_n * 64 + ni * 32 + c31) * PITCH + h * 32 + j * 16);

  f32x16 acc[4][2] = {};
  i64x2 rA[4], rB[2];

  // Prologue: load+write stage 0, issue stage 1 loads.
  #pragma unroll
  for (int a = 0; a < 4; ++a) rA[a] = *(const i64x2*)gA[a];
  #pragma unroll
  for (int b = 0; b < 2; ++b) rB[b] = *(const i64x2*)gB[b];
  #pragma unroll
  for (int a = 0; a < 4; ++a) {
    *(i64*)(smem + wAo[a])      = rA[a].x;
    *(i64*)(smem + wAo[a] + 32) = rA[a].y;
  }
  #pragma unroll
  for (int b = 0; b < 2; ++b) {
    *(i64*)(smem + wBo[b])      = rB[b].x;
    *(i64*)(smem + wBo[b] + 32) = rB[b].y;
  }
  #pragma unroll
  for (int a = 0; a < 4; ++a) rA[a] = *(const i64x2*)(gA[a] + 64);
  #pragma unroll
  for (int b = 0; b < 2; ++b) rB[b] = *(const i64x2*)(gB[b] + 64);
  __syncthreads();

  #pragma unroll 2
  for (int k = 0; k < 16; ++k) {
    const uint32_t sb = (uint32_t)(k & 1) * STAGE;
    const uint32_t nb = STAGE - sb;

    i64x2 af[4][2], bf[2][2];
    #pragma unroll
    for (int mi = 0; mi < 4; ++mi)
      #pragma unroll
      for (int j = 0; j < 2; ++j)
        af[mi][j] = *(const i64x2*)(smem + sb + aoff[mi][j]);
    #pragma unroll
    for (int ni = 0; ni < 2; ++ni)
      #pragma unroll
      for (int j = 0; j < 2; ++j)
        bf[ni][j] = *(const i64x2*)(smem + sb + boff[ni][j]);

    __builtin_amdgcn_sched_barrier(0);  // writes/loads stay below frag reads

    if (k + 1 < 16) {  // ds_write stage k+1 (vmcnt dep on loads from iter k-1)
      #pragma unroll
      for (int a = 0; a < 4; ++a) {
        *(i64*)(smem + nb + wAo[a])      = rA[a].x;
        *(i64*)(smem + nb + wAo[a] + 32) = rA[a].y;
      }
      #pragma unroll
      for (int b = 0; b < 2; ++b) {
        *(i64*)(smem + nb + wBo[b])      = rB[b].x;
        *(i64*)(smem + nb + wBo[b] + 32) = rB[b].y;
      }
    }
    if (k + 2 < 16) {  // issue stage k+2 loads (in flight across next barrier)
      #pragma unroll
      for (int a = 0; a < 4; ++a) rA[a] = *(const i64x2*)(gA[a] + (k + 2) * 64);
      #pragma unroll
      for (int b = 0; b < 2; ++b) rB[b] = *(const i64x2*)(gB[b] + (k + 2) * 64);
    }

    __builtin_amdgcn_sched_barrier(0);  // MFMA phase stays below

    #pragma unroll
    for (int j = 0; j < 2; ++j)
      #pragma unroll
      for (int tt = 0; tt < 2; ++tt)
        #pragma unroll
        for (int mi = 0; mi < 4; ++mi)
          #pragma unroll
          for (int ni = 0; ni < 2; ++ni)
            acc[mi][ni] = __builtin_amdgcn_mfma_f32_32x32x16_fp8_fp8(
                tt ? af[mi][j].y : af[mi][j].x,
                tt ? bf[ni][j].y : bf[ni][j].x,
                acc[mi][ni], 0, 0, 0);

    __syncthreads();
  }

  // Epilogue: descale, exp, row-sum. 32x32 C/D: col = lane&31,
  // row = (reg&3) + 8*(reg>>2) + 4*(lane>>5).
  #pragma unroll
  for (int mi = 0; mi < 4; ++mi) {
    #pragma unroll
    for (int r = 0; r < 16; ++r) {
      float pacc = 0.f;
      #pragma unroll
      for (int ni = 0; ni < 2; ++ni) {
        int v = v0 + wave_n * 64 + ni * 32 + c31;
        float e = __expf(acc[mi][ni][r] * DESCALE);
        pacc += (v < VDIM) ? e : 0.f;   // mask vocab pad
      }
      pacc += __shfl_xor(pacc, 16);
      pacc += __shfl_xor(pacc, 8);
      pacc += __shfl_xor(pacc, 4);
      pacc += __shfl_xor(pacc, 2);
      pacc += __shfl_xor(pacc, 1);
      if (c31 == 0) {
        int row = m0 + wave_m * 128 + mi * 32 + (r & 3) + 8 * (r >> 2) + 4 * h;
        atomicAdd(&S[row], pacc);
      }
    }
  }
}

// ---- final: loss = mean(log(S[n]) - lt[n]) ----
__global__ __launch_bounds__(1024)
void loss_kernel(const float* __restrict__ S, const float* __restrict__ lt,
                 float* __restrict__ out) {
  float s = 0.f;
  for (int n = threadIdx.x; n < NROWS; n += 1024)
    s += logf(S[n]) - lt[n];
  #pragma unroll
  for (int m = 32; m; m >>= 1) s += __shfl_down(s, m);
  __shared__ float red[16];
  if ((threadIdx.x & 63) == 0) red[threadIdx.x >> 6] = s;
  __syncthreads();
  if (threadIdx.x == 0) {
    float t = 0.f;
    #pragma unroll
    for (int i = 0; i < 16; ++i) t += red[i];
    out[0] = t / (float)NROWS;
  }
}

extern "C" void kernel_launch(void* const* d_in, const int* in_sizes, int n_in,
                              void* d_out, int out_size, void* d_ws, size_t ws_size,
                              hipStream_t stream) {
  const float* x = (const float*)d_in[0];   // [4096,1024] fp32
  const float* w = (const float*)d_in[1];   // [50257,1024] fp32
  const int*   t = (const int*)d_in[2];     // [4096] int
  float* out = (float*)d_out;

  char* ws = (char*)d_ws;
  const size_t wq_bytes = (size_t)VPAD * DDIM;    // 51.5 MB fp8
  const size_t xq_bytes = (size_t)NROWS * DDIM;   //  4.2 MB fp8
  uint8_t* wq = (uint8_t*)ws;
  uint8_t* xq = (uint8_t*)(ws + wq_bytes);
  float*   S  = (float*)(ws + wq_bytes + xq_bytes);
  float*   lt = S + NROWS;

  if (ws_size < wq_bytes + xq_bytes + 2 * NROWS * sizeof(float)) return;

  hipMemsetAsync(S, 0, NROWS * sizeof(float), stream);
  cvtq_kernel<<<VPAD / 4, 256, 0, stream>>>(w, (uint32_t*)wq,
                                            (size_t)VDIM * DDIM, 64.0f);
  cvtq_kernel<<<NROWS / 4, 256, 0, stream>>>(x, (uint32_t*)xq,
                                             (size_t)NROWS * DDIM, 8.0f);
  tlogit_kernel<<<NROWS, 256, 0, stream>>>(x, w, t, lt);

  dim3 grid(NMT, NVT);  // (16, 393)
  gemm_lse_kernel<<<grid, 256, 0, stream>>>(xq, wq, S);

  loss_kernel<<<1, 1024, 0, stream>>>(S, lt, out);
}